// Round 19
// baseline (121.517 us; speedup 1.0000x reference)
//
#include <hip/hip_runtime.h>
#include <hip/hip_bf16.h>

#define NN 256
#define CIN 96
#define COUT 96
#define BB 4
#define NBC (BB * CIN)          /* 384 */
#define SEG (NBC * NN)          /* 98304 */

typedef __attribute__((ext_vector_type(8))) short short8;
typedef __attribute__((ext_vector_type(4))) float f32x4;

__device__ __forceinline__ float waveReduceSum(float v) {
    #pragma unroll
    for (int m = 32; m >= 1; m >>= 1) v += __shfl_xor(v, m, 64);
    return v;
}

__device__ __forceinline__ unsigned int packbf2(float lo, float hi) {
    __hip_bfloat162 h = __float22bfloat162_rn(make_float2(lo, hi));
    unsigned int u;
    __builtin_memcpy(&u, &h, 4);
    return u;
}

__device__ __forceinline__ short8 u4_to_s8(uint4 u) {
    short8 r;
    __builtin_memcpy(&r, &u, 16);
    return r;
}

// ---------------- K1: per (b,c) chunked rowsum / colsum-partial / diag / T,S-partial ----
__global__ __launch_bounds__(256) void k_aux(const float* __restrict__ X,
                                             float* __restrict__ rows,
                                             float* __restrict__ diag,
                                             float* __restrict__ colsP,
                                             float* __restrict__ TSp) {
    const int blk = blockIdx.x;
    const int ch = blk & 3, bc = blk >> 2;
    const float* Xp = X + (size_t)bc * (NN * NN) + (size_t)ch * 64 * NN;
    const int tid = threadIdx.x;
    const int w = tid >> 6, lane = tid & 63;

    __shared__ float colPart[4][NN];
    __shared__ float sred[4];

    float4 csum = make_float4(0.f, 0.f, 0.f, 0.f);
    #pragma unroll
    for (int b2 = 0; b2 < 2; ++b2) {
        float4 v[8];
        #pragma unroll
        for (int j = 0; j < 8; ++j) {
            const int r = w * 16 + b2 * 8 + j;
            v[j] = *(const float4*)(Xp + (size_t)r * NN + lane * 4);
        }
        #pragma unroll
        for (int j = 0; j < 8; ++j) {
            csum.x += v[j].x; csum.y += v[j].y; csum.z += v[j].z; csum.w += v[j].w;
            float rs = waveReduceSum(v[j].x + v[j].y + v[j].z + v[j].w);
            if (lane == 0)
                rows[(size_t)bc * NN + ch * 64 + w * 16 + b2 * 8 + j] = rs;
        }
    }
    *(float4*)&colPart[w][lane * 4] = csum;

    if (w == 0) {
        float dv = Xp[(size_t)lane * NN + ch * 64 + lane];
        diag[(size_t)bc * NN + ch * 64 + lane] = dv;
        float t1 = waveReduceSum(dv);
        if (lane == 0) TSp[(ch * NBC + bc) * 2 + 0] = t1;
    }
    __syncthreads();

    float col = colPart[0][tid] + colPart[1][tid] + colPart[2][tid] + colPart[3][tid];
    colsP[(size_t)ch * SEG + (size_t)bc * NN + tid] = col;
    float s1 = waveReduceSum(col);
    if (lane == 0) sred[w] = s1;
    __syncthreads();
    if (tid == 0)
        TSp[(ch * NBC + bc) * 2 + 1] = sred[0] + sred[1] + sred[2] + sred[3];
}

// ---------------- K1b: fold partials + pack weight MFMA fragments ----------------
// wpk entry idx = (s*6+m)*128 + pair*64 + lane; uint4 word j = bf16 pair of
// channels (32s + 8*(lane>>4) + 2j, +1) at o = m*16 + (lane&15). pair0=w8, pair1=w6.
__global__ __launch_bounds__(256) void k_sum(const float* __restrict__ colsP,
                                             const float* __restrict__ TSp,
                                             const float* __restrict__ W,
                                             float* __restrict__ cols,
                                             float* __restrict__ TSa,
                                             uint4* __restrict__ wpk) {
    const int blk = blockIdx.x;
    if (blk < NBC) {
        const int bc = blk;
        const int p = threadIdx.x;
        const size_t base = (size_t)bc * NN + p;
        cols[base] = colsP[0 * (size_t)SEG + base] + colsP[1 * (size_t)SEG + base]
                   + colsP[2 * (size_t)SEG + base] + colsP[3 * (size_t)SEG + base];
        if (p < 2)
            TSa[bc * 2 + p] = TSp[(0 * NBC + bc) * 2 + p] + TSp[(1 * NBC + bc) * 2 + p]
                            + TSp[(2 * NBC + bc) * 2 + p] + TSp[(3 * NBC + bc) * 2 + p];
    } else {
        const int e = (blk - NBC) * 256 + threadIdx.x;    // 0..2303
        if (e < 2304) {
            const int lane = e & 63;
            const int pair = (e >> 6) & 1;
            const int sm = e >> 7;                        // s*6 + m
            const int col = lane & 15, g = lane >> 4;
            const int s = sm / 6, m = sm - s * 6;
            const int o = m * 16 + col;
            const int cb = 32 * s + 8 * g;
            const float* wsrc = W + (pair ? 6 : 8) * CIN * COUT + (size_t)cb * COUT + o;
            uint4 v;
            v.x = packbf2(wsrc[0 * COUT], wsrc[1 * COUT]);
            v.y = packbf2(wsrc[2 * COUT], wsrc[3 * COUT]);
            v.z = packbf2(wsrc[4 * COUT], wsrc[5 * COUT]);
            v.w = packbf2(wsrc[6 * COUT], wsrc[7 * COUT]);
            wpk[e] = v;
        }
    }
}

// ---------------- K2: P' / Q / G' per (b,o,p); 768 blocks (p-split x2), c-split x2 ----
__global__ __launch_bounds__(256) void k_pqg(const float* __restrict__ W,
                                             const float* __restrict__ rows,
                                             const float* __restrict__ cols,
                                             const float* __restrict__ diag,
                                             const float* __restrict__ TSa,
                                             const float* __restrict__ bias,
                                             float* __restrict__ Pw,
                                             float* __restrict__ Qw,
                                             float* __restrict__ Gw) {
    const int blk = blockIdx.x;
    const int bo = blk >> 1, ph = blk & 1;
    const int b = bo / COUT, o = bo % COUT;
    const int half = threadIdx.x >> 7;
    const int pl = threadIdx.x & 127;
    const int p = ph * 128 + pl;

    __shared__ float red[5][128];

    float P = 0.f, Q = 0.f, G = 0.f, s = 0.f, gs = 0.f;
    const int cbeg = half * 48, cend = cbeg + 48;
    for (int c = cbeg; c < cend; ++c) {
        const int bcq = b * CIN + c;
        const size_t base = (size_t)bcq * NN;
        float r  = rows[base + p];
        float cl = cols[base + p];
        float dg = diag[base + p];
        const float* wp = W + c * COUT + o;
        #define WI(i) wp[(i) * CIN * COUT]
        P += WI(12) * r + WI(7)  * cl + WI(5) * dg;
        Q += WI(13) * r + WI(10) * cl + WI(9) * dg;
        G += WI(3)  * r + WI(1)  * cl + WI(0) * dg;
        float Tv = TSa[bcq * 2 + 0];
        float Sv = TSa[bcq * 2 + 1];
        s  += WI(11) * Tv + WI(14) * Sv;
        gs += WI(2)  * Tv + WI(4)  * Sv;
        #undef WI
    }
    if (half == 1) {
        red[0][pl] = P; red[1][pl] = Q; red[2][pl] = G; red[3][pl] = s; red[4][pl] = gs;
    }
    __syncthreads();
    if (half == 0) {
        P += red[0][pl]; Q += red[1][pl]; G += red[2][pl]; s += red[3][pl]; gs += red[4][pl];
        const size_t ob = (size_t)bo * NN;
        Pw[ob + p] = P + s + bias[0];
        Qw[ob + p] = Q;
        Gw[ob + p] = G + gs;
    }
}

// ---------------- K3: MFMA channel-mix; r16 kstep structure, TWO adjacent-tq
// tiles per block (512 blocks): tile2's first loads issue before tile1's
// epilogue -> epilogue store burst overlaps tile2 pipeline fill. ----
#define XAPLANE 260
#define XBPLANE 324

__global__ __launch_bounds__(512, 1) void k_main(const float* __restrict__ X,
                                                 const uint4* __restrict__ wpk,
                                                 const float* __restrict__ Pw,
                                                 const float* __restrict__ Qw,
                                                 const float* __restrict__ Gw,
                                                 float* __restrict__ Y) {
    __shared__ __align__(16) unsigned int XAs[16 * XAPLANE];
    __shared__ __align__(16) unsigned int XBs[16 * XBPLANE];
    __shared__ __align__(16) uint4 Wf[2304];   // 36.9 KB, all 3 ksteps' frags

    // bijective XCD swizzle over 512 blocks; each block owns work {2k, 2k+1}
    // (same tp,b; adjacent tq -> tile2 rows share tile1's cache lines)
    const int orig = blockIdx.x;                 // 0..511
    const int kk = (orig & 7) * 64 + (orig >> 3);
    const int W0 = kk << 1;
    const int tq0 = W0 & 15, tp = (W0 >> 4) & 15, b = W0 >> 8;

    const int tid = threadIdx.x;
    const int w = tid >> 6, lane = tid & 63;
    const int sp = lane >> 2, sq4 = (lane & 3) * 4;
    const int col = lane & 15, g = lane >> 4;

    const float* Xb  = X + (size_t)b * CIN * NN * NN;
    const float* G1a = Xb + (size_t)(tp * 16) * NN + tq0 * 16;
    const float* G2a = Xb + (size_t)(tq0 * 16) * NN + tp * 16;
    const float* G1b = G1a + 16;        // tq0+1: next 16 cols, same rows
    const float* G2b = G2a + 16 * NN;   // tq0+1: next 16 rows

    const int cw0 = w, cw1 = w + 8;

    float4 a00, a01, b00, b01;
    float4 a10, a11, b10, b11;

    #define LOADG(G1X, G2X, C0) { \
        const size_t cb0 = (size_t)((C0) + 2 * cw0) * (NN * NN); \
        const size_t cb1 = (size_t)((C0) + 2 * cw1) * (NN * NN); \
        const float* pa0 = (G1X) + cb0 + sp * NN + sq4; \
        a00 = *(const float4*)pa0; \
        a01 = *(const float4*)(pa0 + NN * NN); \
        const float* pb0 = (G2X) + cb0 + sp * NN + sq4; \
        b00 = *(const float4*)pb0; \
        b01 = *(const float4*)(pb0 + NN * NN); \
        const float* pa1 = (G1X) + cb1 + sp * NN + sq4; \
        a10 = *(const float4*)pa1; \
        a11 = *(const float4*)(pa1 + NN * NN); \
        const float* pb1 = (G2X) + cb1 + sp * NN + sq4; \
        b10 = *(const float4*)pb1; \
        b11 = *(const float4*)(pb1 + NN * NN); }

    #define PACKSTORE() { \
        uint4 pk; \
        pk.x = packbf2(a00.x, a01.x); \
        pk.y = packbf2(a00.y, a01.y); \
        pk.z = packbf2(a00.z, a01.z); \
        pk.w = packbf2(a00.w, a01.w); \
        *(uint4*)&XAs[cw0 * XAPLANE + sp * 16 + sq4] = pk; \
        pk.x = packbf2(a10.x, a11.x); \
        pk.y = packbf2(a10.y, a11.y); \
        pk.z = packbf2(a10.z, a11.z); \
        pk.w = packbf2(a10.w, a11.w); \
        *(uint4*)&XAs[cw1 * XAPLANE + sp * 16 + sq4] = pk; \
        unsigned int* dB0 = &XBs[cw0 * XBPLANE + sp]; \
        dB0[(sq4 + 0) * 20] = packbf2(b00.x, b01.x); \
        dB0[(sq4 + 1) * 20] = packbf2(b00.y, b01.y); \
        dB0[(sq4 + 2) * 20] = packbf2(b00.z, b01.z); \
        dB0[(sq4 + 3) * 20] = packbf2(b00.w, b01.w); \
        unsigned int* dB1 = &XBs[cw1 * XBPLANE + sp]; \
        dB1[(sq4 + 0) * 20] = packbf2(b10.x, b11.x); \
        dB1[(sq4 + 1) * 20] = packbf2(b10.y, b11.y); \
        dB1[(sq4 + 2) * 20] = packbf2(b10.z, b11.z); \
        dB1[(sq4 + 3) * 20] = packbf2(b10.w, b11.w); }

    #define MSTEP(M) { \
        short8 w8f = u4_to_s8(wb[(M) * 128]); \
        short8 w6f = u4_to_s8(wb[(M) * 128 + 64]); \
        acc[M][0] = __builtin_amdgcn_mfma_f32_16x16x32_bf16(xd0, w8f, acc[M][0], 0, 0, 0); \
        acc[M][0] = __builtin_amdgcn_mfma_f32_16x16x32_bf16(xt0, w6f, acc[M][0], 0, 0, 0); \
        acc[M][1] = __builtin_amdgcn_mfma_f32_16x16x32_bf16(xd1, w8f, acc[M][1], 0, 0, 0); \
        acc[M][1] = __builtin_amdgcn_mfma_f32_16x16x32_bf16(xt1, w6f, acc[M][1], 0, 0, 0); }

    #define KCOMPUTE(S) { \
        const unsigned int* xab = &XAs[4 * g * XAPLANE + w * 16 + col]; \
        const unsigned int* xbb = &XBs[4 * g * XBPLANE + w * 20 + col]; \
        uint4 u; \
        u.x = xab[0]; u.y = xab[XAPLANE]; u.z = xab[2 * XAPLANE]; u.w = xab[3 * XAPLANE]; \
        short8 xd0 = u4_to_s8(u); \
        u.x = xab[128]; u.y = xab[XAPLANE + 128]; u.z = xab[2 * XAPLANE + 128]; u.w = xab[3 * XAPLANE + 128]; \
        short8 xd1 = u4_to_s8(u); \
        u.x = xbb[0]; u.y = xbb[XBPLANE]; u.z = xbb[2 * XBPLANE]; u.w = xbb[3 * XBPLANE]; \
        short8 xt0 = u4_to_s8(u); \
        u.x = xbb[160]; u.y = xbb[XBPLANE + 160]; u.z = xbb[2 * XBPLANE + 160]; u.w = xbb[3 * XBPLANE + 160]; \
        short8 xt1 = u4_to_s8(u); \
        const uint4* wb = &Wf[(S) * 768 + lane]; \
        MSTEP(0) MSTEP(1) MSTEP(2) MSTEP(3) MSTEP(4) MSTEP(5) }

    #define KSTEP(S, DOLOAD, G1X, G2X, C0) { \
        __syncthreads(); \
        PACKSTORE(); \
        __syncthreads(); \
        if (DOLOAD) { LOADG(G1X, G2X, C0); } \
        KCOMPUTE(S) }

    #define EPI_TILE(TQ) { \
        const int p0 = tp * 16 + w; \
        const int q4 = (TQ) * 16 + g * 4; \
        const bool diagblk = (tp == (TQ)); \
        _Pragma("unroll") \
        for (int m = 0; m < 6; ++m) { \
            const int o = m * 16 + col; \
            const size_t ob = (size_t)(b * COUT + o) * NN; \
            const float4 qf = *(const float4*)&Qw[ob + q4]; \
            _Pragma("unroll") \
            for (int rr = 0; rr < 2; ++rr) { \
                const int p = p0 + rr * 8; \
                const float pv = Pw[ob + p]; \
                float4 out; \
                out.x = acc[m][rr][0] + pv + qf.x; \
                out.y = acc[m][rr][1] + pv + qf.y; \
                out.z = acc[m][rr][2] + pv + qf.z; \
                out.w = acc[m][rr][3] + pv + qf.w; \
                if (diagblk) { \
                    const float gv = Gw[ob + p]; \
                    const int d = (p & 15) - g * 4; \
                    if (d == 0) out.x += gv; \
                    else if (d == 1) out.y += gv; \
                    else if (d == 2) out.z += gv; \
                    else if (d == 3) out.w += gv; \
                } \
                *(float4*)&Y[(ob + p) * NN + q4] = out; \
            } \
        } }

    // prologue: tile-a kstep-0 loads in flight, then Wf L2->LDS copy
    LOADG(G1a, G2a, 0);
    for (int iw = tid; iw < 2304; iw += 512) Wf[iw] = wpk[iw];

    f32x4 acc[6][2];
    #pragma unroll
    for (int m = 0; m < 6; ++m) {
        acc[m][0] = f32x4{0.f, 0.f, 0.f, 0.f};
        acc[m][1] = f32x4{0.f, 0.f, 0.f, 0.f};
    }

    // ---- tile a (tq0) ----
    KSTEP(0, 1, G1a, G2a, 32)
    KSTEP(1, 1, G1a, G2a, 64)
    KSTEP(2, 1, G1b, G2b, 0)     // issue tile b's first loads BEFORE epilogue a
    EPI_TILE(tq0)

    #pragma unroll
    for (int m = 0; m < 6; ++m) {
        acc[m][0] = f32x4{0.f, 0.f, 0.f, 0.f};
        acc[m][1] = f32x4{0.f, 0.f, 0.f, 0.f};
    }

    // ---- tile b (tq0+1) ----
    KSTEP(0, 1, G1b, G2b, 32)
    KSTEP(1, 1, G1b, G2b, 64)
    KSTEP(2, 0, G1b, G2b, 0)
    EPI_TILE(tq0 + 1)

    #undef EPI_TILE
    #undef KSTEP
    #undef KCOMPUTE
    #undef MSTEP
    #undef PACKSTORE
    #undef LOADG
}

extern "C" void kernel_launch(void* const* d_in, const int* in_sizes, int n_in,
                              void* d_out, int out_size, void* d_ws, size_t ws_size,
                              hipStream_t stream) {
    const float* X    = (const float*)d_in[0];
    const float* W    = (const float*)d_in[2];   // [15][96][96]
    const float* bias = (const float*)d_in[3];
    float* Y = (float*)d_out;

    float* ws    = (float*)d_ws;
    float* rows  = ws;
    float* diag  = ws + (size_t)SEG;
    float* colsP = ws + 2 * (size_t)SEG;          // 4 chunks
    float* Pw    = ws + 6 * (size_t)SEG;
    float* Qw    = ws + 7 * (size_t)SEG;
    float* Gw    = ws + 8 * (size_t)SEG;
    float* TSp   = ws + 9 * (size_t)SEG;          // 4*NBC*2 floats
    float* TSa   = ws + 9 * (size_t)SEG + 4096;   // NBC*2 floats
    float* cols  = ws + 10 * (size_t)SEG;
    uint4* wpk   = (uint4*)(ws + 11 * (size_t)SEG);  // 2304 uint4 = 36.9 KB

    k_aux<<<NBC * 4, 256, 0, stream>>>(X, rows, diag, colsP, TSp);
    k_sum<<<NBC + 9, 256, 0, stream>>>(colsP, TSp, W, cols, TSa, wpk);
    k_pqg<<<BB * COUT * 2, 256, 0, stream>>>(W, rows, cols, diag, TSa, bias, Pw, Qw, Gw);
    k_main<<<512, 512, 0, stream>>>(X, wpk, Pw, Qw, Gw, Y);
}

// Round 20
// 103.006 us; speedup vs baseline: 1.1797x; 1.1797x over previous
//
#include <hip/hip_runtime.h>
#include <hip/hip_bf16.h>

#define NN 256
#define CIN 96
#define COUT 96
#define BB 4
#define NBC (BB * CIN)          /* 384 */
#define SEG (NBC * NN)          /* 98304 */

typedef __attribute__((ext_vector_type(8))) short short8;
typedef __attribute__((ext_vector_type(4))) float f32x4;

__device__ __forceinline__ float waveReduceSum(float v) {
    #pragma unroll
    for (int m = 32; m >= 1; m >>= 1) v += __shfl_xor(v, m, 64);
    return v;
}

__device__ __forceinline__ unsigned int packbf2(float lo, float hi) {
    __hip_bfloat162 h = __float22bfloat162_rn(make_float2(lo, hi));
    unsigned int u;
    __builtin_memcpy(&u, &h, 4);
    return u;
}

__device__ __forceinline__ short8 u4_to_s8(uint4 u) {
    short8 r;
    __builtin_memcpy(&r, &u, 16);
    return r;
}

// ---------------- K1: per (b,c) chunked rowsum / colsum-partial / diag / T,S-partial ----
__global__ __launch_bounds__(256) void k_aux(const float* __restrict__ X,
                                             float* __restrict__ rows,
                                             float* __restrict__ diag,
                                             float* __restrict__ colsP,
                                             float* __restrict__ TSp) {
    const int blk = blockIdx.x;
    const int ch = blk & 3, bc = blk >> 2;
    const float* Xp = X + (size_t)bc * (NN * NN) + (size_t)ch * 64 * NN;
    const int tid = threadIdx.x;
    const int w = tid >> 6, lane = tid & 63;

    __shared__ float colPart[4][NN];
    __shared__ float sred[4];

    float4 csum = make_float4(0.f, 0.f, 0.f, 0.f);
    #pragma unroll
    for (int b2 = 0; b2 < 2; ++b2) {
        float4 v[8];
        #pragma unroll
        for (int j = 0; j < 8; ++j) {
            const int r = w * 16 + b2 * 8 + j;
            v[j] = *(const float4*)(Xp + (size_t)r * NN + lane * 4);
        }
        #pragma unroll
        for (int j = 0; j < 8; ++j) {
            csum.x += v[j].x; csum.y += v[j].y; csum.z += v[j].z; csum.w += v[j].w;
            float rs = waveReduceSum(v[j].x + v[j].y + v[j].z + v[j].w);
            if (lane == 0)
                rows[(size_t)bc * NN + ch * 64 + w * 16 + b2 * 8 + j] = rs;
        }
    }
    *(float4*)&colPart[w][lane * 4] = csum;

    if (w == 0) {
        float dv = Xp[(size_t)lane * NN + ch * 64 + lane];
        diag[(size_t)bc * NN + ch * 64 + lane] = dv;
        float t1 = waveReduceSum(dv);
        if (lane == 0) TSp[(ch * NBC + bc) * 2 + 0] = t1;
    }
    __syncthreads();

    float col = colPart[0][tid] + colPart[1][tid] + colPart[2][tid] + colPart[3][tid];
    colsP[(size_t)ch * SEG + (size_t)bc * NN + tid] = col;
    float s1 = waveReduceSum(col);
    if (lane == 0) sred[w] = s1;
    __syncthreads();
    if (tid == 0)
        TSp[(ch * NBC + bc) * 2 + 1] = sred[0] + sred[1] + sred[2] + sred[3];
}

// ---------------- K1b: fold partials + pack weight MFMA fragments ----------------
// wpk entry idx = (s*6+m)*128 + pair*64 + lane; uint4 word j = bf16 pair of
// channels (32s + 8*(lane>>4) + 2j, +1) at o = m*16 + (lane&15). pair0=w8, pair1=w6.
__global__ __launch_bounds__(256) void k_sum(const float* __restrict__ colsP,
                                             const float* __restrict__ TSp,
                                             const float* __restrict__ W,
                                             float* __restrict__ cols,
                                             float* __restrict__ TSa,
                                             uint4* __restrict__ wpk) {
    const int blk = blockIdx.x;
    if (blk < NBC) {
        const int bc = blk;
        const int p = threadIdx.x;
        const size_t base = (size_t)bc * NN + p;
        cols[base] = colsP[0 * (size_t)SEG + base] + colsP[1 * (size_t)SEG + base]
                   + colsP[2 * (size_t)SEG + base] + colsP[3 * (size_t)SEG + base];
        if (p < 2)
            TSa[bc * 2 + p] = TSp[(0 * NBC + bc) * 2 + p] + TSp[(1 * NBC + bc) * 2 + p]
                            + TSp[(2 * NBC + bc) * 2 + p] + TSp[(3 * NBC + bc) * 2 + p];
    } else {
        const int e = (blk - NBC) * 256 + threadIdx.x;    // 0..2303
        if (e < 2304) {
            const int lane = e & 63;
            const int pair = (e >> 6) & 1;
            const int sm = e >> 7;                        // s*6 + m
            const int col = lane & 15, g = lane >> 4;
            const int s = sm / 6, m = sm - s * 6;
            const int o = m * 16 + col;
            const int cb = 32 * s + 8 * g;
            const float* wsrc = W + (pair ? 6 : 8) * CIN * COUT + (size_t)cb * COUT + o;
            uint4 v;
            v.x = packbf2(wsrc[0 * COUT], wsrc[1 * COUT]);
            v.y = packbf2(wsrc[2 * COUT], wsrc[3 * COUT]);
            v.z = packbf2(wsrc[4 * COUT], wsrc[5 * COUT]);
            v.w = packbf2(wsrc[6 * COUT], wsrc[7 * COUT]);
            wpk[e] = v;
        }
    }
}

// ---------------- K2: P' / Q / G' per (b,o,p); 768 blocks (p-split x2), c-split x2 ----
__global__ __launch_bounds__(256) void k_pqg(const float* __restrict__ W,
                                             const float* __restrict__ rows,
                                             const float* __restrict__ cols,
                                             const float* __restrict__ diag,
                                             const float* __restrict__ TSa,
                                             const float* __restrict__ bias,
                                             float* __restrict__ Pw,
                                             float* __restrict__ Qw,
                                             float* __restrict__ Gw) {
    const int blk = blockIdx.x;
    const int bo = blk >> 1, ph = blk & 1;
    const int b = bo / COUT, o = bo % COUT;
    const int half = threadIdx.x >> 7;
    const int pl = threadIdx.x & 127;
    const int p = ph * 128 + pl;

    __shared__ float red[5][128];

    float P = 0.f, Q = 0.f, G = 0.f, s = 0.f, gs = 0.f;
    const int cbeg = half * 48, cend = cbeg + 48;
    for (int c = cbeg; c < cend; ++c) {
        const int bcq = b * CIN + c;
        const size_t base = (size_t)bcq * NN;
        float r  = rows[base + p];
        float cl = cols[base + p];
        float dg = diag[base + p];
        const float* wp = W + c * COUT + o;
        #define WI(i) wp[(i) * CIN * COUT]
        P += WI(12) * r + WI(7)  * cl + WI(5) * dg;
        Q += WI(13) * r + WI(10) * cl + WI(9) * dg;
        G += WI(3)  * r + WI(1)  * cl + WI(0) * dg;
        float Tv = TSa[bcq * 2 + 0];
        float Sv = TSa[bcq * 2 + 1];
        s  += WI(11) * Tv + WI(14) * Sv;
        gs += WI(2)  * Tv + WI(4)  * Sv;
        #undef WI
    }
    if (half == 1) {
        red[0][pl] = P; red[1][pl] = Q; red[2][pl] = G; red[3][pl] = s; red[4][pl] = gs;
    }
    __syncthreads();
    if (half == 0) {
        P += red[0][pl]; Q += red[1][pl]; G += red[2][pl]; s += red[3][pl]; gs += red[4][pl];
        const size_t ob = (size_t)bo * NN;
        Pw[ob + p] = P + s + bias[0];
        Qw[ob + p] = Q;
        Gw[ob + p] = G + gs;
    }
}

// ---------------- K3: MFMA channel-mix; r9 structure (LOADG after barrier 2),
// one-time Wf LDS copy, compact XA, r9 XCD swizzle ----
#define XAPLANE 260
#define XBPLANE 324

__global__ __launch_bounds__(512, 1) void k_main(const float* __restrict__ X,
                                                 const uint4* __restrict__ wpk,
                                                 const float* __restrict__ Pw,
                                                 const float* __restrict__ Qw,
                                                 const float* __restrict__ Gw,
                                                 float* __restrict__ Y) {
    __shared__ __align__(16) unsigned int XAs[16 * XAPLANE];
    __shared__ __align__(16) unsigned int XBs[16 * XBPLANE];
    __shared__ __align__(16) uint4 Wf[2304];   // 36.9 KB, all 3 ksteps' frags

    // r9 bijective XCD swizzle (best measured FETCH)
    const int orig = blockIdx.x + 16 * (blockIdx.y + 16 * blockIdx.z);
    const int work = (orig & 7) * 128 + (orig >> 3);
    const int tq = work & 15, tp = (work >> 4) & 15, b = work >> 8;

    const int tid = threadIdx.x;
    const int w = tid >> 6, lane = tid & 63;
    const int sp = lane >> 2, sq4 = (lane & 3) * 4;
    const int col = lane & 15, g = lane >> 4;

    const float* Xb  = X + (size_t)b * CIN * NN * NN;
    const float* G1  = Xb + (size_t)(tp * 16) * NN + tq * 16;
    const float* G2  = Xb + (size_t)(tq * 16) * NN + tp * 16;

    const int cw0 = w, cw1 = w + 8;

    float4 a00, a01, b00, b01;
    float4 a10, a11, b10, b11;

    #define LOADG(C0) { \
        const size_t cb0 = (size_t)((C0) + 2 * cw0) * (NN * NN); \
        const size_t cb1 = (size_t)((C0) + 2 * cw1) * (NN * NN); \
        const float* pa0 = G1 + cb0 + sp * NN + sq4; \
        a00 = *(const float4*)pa0; \
        a01 = *(const float4*)(pa0 + NN * NN); \
        const float* pb0 = G2 + cb0 + sp * NN + sq4; \
        b00 = *(const float4*)pb0; \
        b01 = *(const float4*)(pb0 + NN * NN); \
        const float* pa1 = G1 + cb1 + sp * NN + sq4; \
        a10 = *(const float4*)pa1; \
        a11 = *(const float4*)(pa1 + NN * NN); \
        const float* pb1 = G2 + cb1 + sp * NN + sq4; \
        b10 = *(const float4*)pb1; \
        b11 = *(const float4*)(pb1 + NN * NN); }

    // issue the first HBM tile loads, THEN the Wf L2 copy (overlaps latency)
    LOADG(0);
    for (int iw = tid; iw < 2304; iw += 512) Wf[iw] = wpk[iw];

    f32x4 acc[6][2];
    #pragma unroll
    for (int m = 0; m < 6; ++m) {
        acc[m][0] = f32x4{0.f, 0.f, 0.f, 0.f};
        acc[m][1] = f32x4{0.f, 0.f, 0.f, 0.f};
    }

    #pragma unroll
    for (int s = 0; s < 3; ++s) {
        __syncthreads();   // prev iter's LDS reads complete (also covers Wf copy)

        // ---- pack + store prefetched X ----
        {
            uint4 pk;
            pk.x = packbf2(a00.x, a01.x);
            pk.y = packbf2(a00.y, a01.y);
            pk.z = packbf2(a00.z, a01.z);
            pk.w = packbf2(a00.w, a01.w);
            *(uint4*)&XAs[cw0 * XAPLANE + sp * 16 + sq4] = pk;
            pk.x = packbf2(a10.x, a11.x);
            pk.y = packbf2(a10.y, a11.y);
            pk.z = packbf2(a10.z, a11.z);
            pk.w = packbf2(a10.w, a11.w);
            *(uint4*)&XAs[cw1 * XAPLANE + sp * 16 + sq4] = pk;
            unsigned int* dB0 = &XBs[cw0 * XBPLANE + sp];
            dB0[(sq4 + 0) * 20] = packbf2(b00.x, b01.x);
            dB0[(sq4 + 1) * 20] = packbf2(b00.y, b01.y);
            dB0[(sq4 + 2) * 20] = packbf2(b00.z, b01.z);
            dB0[(sq4 + 3) * 20] = packbf2(b00.w, b01.w);
            unsigned int* dB1 = &XBs[cw1 * XBPLANE + sp];
            dB1[(sq4 + 0) * 20] = packbf2(b10.x, b11.x);
            dB1[(sq4 + 1) * 20] = packbf2(b10.y, b11.y);
            dB1[(sq4 + 2) * 20] = packbf2(b10.z, b11.z);
            dB1[(sq4 + 3) * 20] = packbf2(b10.w, b11.w);
        }
        __syncthreads();

        // ---- issue next tile's global loads AFTER barrier (overlap ds_read + MFMA) ----
        if (s < 2) LOADG(32 * (s + 1));

        const unsigned int* xab = &XAs[4 * g * XAPLANE + w * 16 + col];
        const unsigned int* xbb = &XBs[4 * g * XBPLANE + w * 20 + col];
        uint4 u;
        u.x = xab[0]; u.y = xab[XAPLANE]; u.z = xab[2 * XAPLANE]; u.w = xab[3 * XAPLANE];
        short8 xd0 = u4_to_s8(u);
        u.x = xab[128]; u.y = xab[XAPLANE + 128]; u.z = xab[2 * XAPLANE + 128]; u.w = xab[3 * XAPLANE + 128];
        short8 xd1 = u4_to_s8(u);
        u.x = xbb[0]; u.y = xbb[XBPLANE]; u.z = xbb[2 * XBPLANE]; u.w = xbb[3 * XBPLANE];
        short8 xt0 = u4_to_s8(u);
        u.x = xbb[160]; u.y = xbb[XBPLANE + 160]; u.z = xbb[2 * XBPLANE + 160]; u.w = xbb[3 * XBPLANE + 160];
        short8 xt1 = u4_to_s8(u);

        const uint4* wb = &Wf[s * 768 + lane];
        #define MSTEP(M) { \
            short8 w8f = u4_to_s8(wb[(M) * 128]); \
            short8 w6f = u4_to_s8(wb[(M) * 128 + 64]); \
            acc[M][0] = __builtin_amdgcn_mfma_f32_16x16x32_bf16(xd0, w8f, acc[M][0], 0, 0, 0); \
            acc[M][0] = __builtin_amdgcn_mfma_f32_16x16x32_bf16(xt0, w6f, acc[M][0], 0, 0, 0); \
            acc[M][1] = __builtin_amdgcn_mfma_f32_16x16x32_bf16(xd1, w8f, acc[M][1], 0, 0, 0); \
            acc[M][1] = __builtin_amdgcn_mfma_f32_16x16x32_bf16(xt1, w6f, acc[M][1], 0, 0, 0); }
        MSTEP(0)
        MSTEP(1)
        MSTEP(2)
        MSTEP(3)
        MSTEP(4)
        MSTEP(5)
        #undef MSTEP
    }
    #undef LOADG

    // ---- r9 epilogue (per-m, proven) ----
    const int p0 = tp * 16 + w;
    const int q4 = tq * 16 + g * 4;
    const bool diagblk = (tp == tq);
    #pragma unroll
    for (int m = 0; m < 6; ++m) {
        const int o = m * 16 + col;
        const size_t ob = (size_t)(b * COUT + o) * NN;
        const float4 qf = *(const float4*)&Qw[ob + q4];
        #pragma unroll
        for (int rr = 0; rr < 2; ++rr) {
            const int p = p0 + rr * 8;
            const float pv = Pw[ob + p];
            float4 out;
            out.x = acc[m][rr][0] + pv + qf.x;
            out.y = acc[m][rr][1] + pv + qf.y;
            out.z = acc[m][rr][2] + pv + qf.z;
            out.w = acc[m][rr][3] + pv + qf.w;
            if (diagblk) {
                const float gv = Gw[ob + p];
                const int d = (p & 15) - g * 4;
                if (d == 0) out.x += gv;
                else if (d == 1) out.y += gv;
                else if (d == 2) out.z += gv;
                else if (d == 3) out.w += gv;
            }
            *(float4*)&Y[(ob + p) * NN + q4] = out;
        }
    }
}

extern "C" void kernel_launch(void* const* d_in, const int* in_sizes, int n_in,
                              void* d_out, int out_size, void* d_ws, size_t ws_size,
                              hipStream_t stream) {
    const float* X    = (const float*)d_in[0];
    const float* W    = (const float*)d_in[2];   // [15][96][96]
    const float* bias = (const float*)d_in[3];
    float* Y = (float*)d_out;

    float* ws    = (float*)d_ws;
    float* rows  = ws;
    float* diag  = ws + (size_t)SEG;
    float* colsP = ws + 2 * (size_t)SEG;          // 4 chunks
    float* Pw    = ws + 6 * (size_t)SEG;
    float* Qw    = ws + 7 * (size_t)SEG;
    float* Gw    = ws + 8 * (size_t)SEG;
    float* TSp   = ws + 9 * (size_t)SEG;          // 4*NBC*2 floats
    float* TSa   = ws + 9 * (size_t)SEG + 4096;   // NBC*2 floats
    float* cols  = ws + 10 * (size_t)SEG;
    uint4* wpk   = (uint4*)(ws + 11 * (size_t)SEG);  // 2304 uint4 = 36.9 KB

    k_aux<<<NBC * 4, 256, 0, stream>>>(X, rows, diag, colsP, TSp);
    k_sum<<<NBC + 9, 256, 0, stream>>>(colsP, TSp, W, cols, TSa, wpk);
    k_pqg<<<BB * COUT * 2, 256, 0, stream>>>(W, rows, cols, diag, TSa, bias, Pw, Qw, Gw);
    k_main<<<dim3(16, 16, BB), 512, 0, stream>>>(X, wpk, Pw, Qw, Gw, Y);
}